// Round 6
// baseline (112.255 us; speedup 1.0000x reference)
//
#include <hip/hip_runtime.h>
#include <hip/hip_bf16.h>

// Correlation loss, fully folded into bf16 MFMA (r4 math), with r6 staging:
// async global->LDS DMA (global_load_lds width 4) into fp32 [ch][p] layout —
// zero VGPR pressure, all 35 channel loads in flight, ONE latency wait.
// Then a register-light LDS convert pass builds the bf16 fragments:
//   MFMA1: A = -2*m*msi~, B = m*msi~             -> -2 m m g_m
//   MFMA2: A = m*{2h~,s_hi,s_lo,1,1,0}, B = m*{h~,1,1,s_hi,s_lo,0}
//          -> m m (2 g_h + s_p + s_q)
// acc += |g[reg]|; partials to d_ws; tiny reduce kernel writes out.

#define PSZ  256
#define IMG  512
#define IMG2 (IMG * IMG)
#define XSTR 40          // ushorts per xs row = 80 B (16B-aligned)

typedef __attribute__((ext_vector_type(8))) short short8;
typedef __attribute__((ext_vector_type(4))) float float4v;

static __device__ __forceinline__ unsigned short f2bf(float v) {
    union { __hip_bfloat16 b; unsigned short u; } cv;
    cv.b = __float2bfloat16(v);
    return cv.u;
}
static __device__ __forceinline__ float bf2f(unsigned short u) {
    union { unsigned int u; float f; } cv;
    cv.u = ((unsigned int)u) << 16;
    return cv.f;
}
// lane-wise global gather -> LDS (uniform base + lane*4), no VGPR round-trip
static __device__ __forceinline__ void gl_lds4(const float* g, float* l) {
    __builtin_amdgcn_global_load_lds(
        (const __attribute__((address_space(1))) void*)g,
        (__attribute__((address_space(3))) void*)l, 4, 0, 0);
}

__global__ __launch_bounds__(256, 2)
void corr_loss_kernel(const float* __restrict__ msi,
                      const float* __restrict__ he,
                      const int* __restrict__ i_idx,
                      const int* __restrict__ j_idx,
                      float* __restrict__ partial)
{
    __shared__ __align__(16) float          xf[35 * PSZ];    // 35840 B fp32 [ch][p]
    __shared__ __align__(16) unsigned short xs[PSZ * XSTR];  // 20480 B m*bf16(msi) [p][k]
    __shared__ __align__(16) unsigned short eA[PSZ * 8];     // 4096 B
    __shared__ __align__(16) unsigned short eB[PSZ * 8];     // 4096 B
    __shared__ float red[4];

    const int b = blockIdx.x;
    const int t = threadIdx.x;
    const int i0 = i_idx[b], j0 = j_idx[b];
    const int lane = t & 63, w = t >> 6;

    // ---- async staging: wave w DMAs channels {w, w+4, ...}; 4 segs/channel ----
    {
        const int r = lane >> 4, c = lane & 15;
        const size_t po = (size_t)(i0 + r) * IMG + (size_t)(j0 + c);
        for (int ch = w; ch < 35; ch += 4) {
            const float* gb = (ch < 32) ? (msi + (size_t)ch * IMG2 + po)
                                        : (he + (size_t)(ch - 32) * IMG2 + po);
            float* lb = &xf[ch * PSZ];
#pragma unroll
            for (int seg = 0; seg < 4; ++seg)         // pixels seg*64 + lane
                gl_lds4(gb + (size_t)(seg * 4) * IMG, lb + seg * 64);
        }
    }
    __builtin_amdgcn_s_waitcnt(0);    // drain this wave's LDS-DMA
    __syncthreads();                  // all waves' channels visible

    // ---- convert column p = t (reads bank-friendly stride-PSZ columns) ----
    {
        const float h0 = xf[32 * PSZ + t], h1 = xf[33 * PSZ + t], h2 = xf[34 * PSZ + t];
        const float mf = (h0 + h1 + h2 >= 0.05f) ? 1.f : 0.f;   // mask: exact fp32
        const unsigned short hb0 = f2bf(h0 * mf), hb1 = f2bf(h1 * mf), hb2 = f2bf(h2 * mf);
        const float hr0 = bf2f(hb0), hr1 = bf2f(hb1), hr2 = bf2f(hb2);
        const float sh = hr0 * hr0 + hr1 * hr1 + hr2 * hr2;

        float sm = 0.f;
#pragma unroll
        for (int g = 0; g < 4; ++g) {
            unsigned int pk[4];
#pragma unroll
            for (int k = 0; k < 4; ++k) {
                unsigned short lo = f2bf(xf[(g * 8 + 2 * k)     * PSZ + t] * mf);
                unsigned short hi = f2bf(xf[(g * 8 + 2 * k + 1) * PSZ + t] * mf);
                float fl = bf2f(lo), fh = bf2f(hi);
                sm = fmaf(fl, fl, sm);
                sm = fmaf(fh, fh, sm);
                pk[k] = (unsigned int)lo | ((unsigned int)hi << 16);
            }
            *(uint4*)&xs[t * XSTR + g * 8] = make_uint4(pk[0], pk[1], pk[2], pk[3]);
        }
        const float s = sm - sh;
        const unsigned short shi = f2bf(s);
        const unsigned short slo = f2bf(s - bf2f(shi));
        const unsigned short mb  = (mf != 0.f) ? (unsigned short)0x3F80 : (unsigned short)0;
        const unsigned short d0  = f2bf(2.f * hr0);   // exact: exponent+1
        const unsigned short d1  = f2bf(2.f * hr1);
        const unsigned short d2  = f2bf(2.f * hr2);
        *(uint4*)&eA[t * 8] = make_uint4(          // {2h0,2h1,2h2,s_hi,s_lo,m,m,0}
            (unsigned)d0 | ((unsigned)d1 << 16),
            (unsigned)d2 | ((unsigned)shi << 16),
            (unsigned)slo | ((unsigned)mb << 16),
            (unsigned)mb);
        *(uint4*)&eB[t * 8] = make_uint4(          // {h0,h1,h2,m,m,s_hi,s_lo,0}
            (unsigned)hb0 | ((unsigned)hb1 << 16),
            (unsigned)hb2 | ((unsigned)mb << 16),
            (unsigned)mb | ((unsigned)shi << 16),
            (unsigned)slo);
    }
    __syncthreads();

    const int mrow = lane & 15, quad = lane >> 4;
    const short8 zfrag = {0, 0, 0, 0, 0, 0, 0, 0};

    // hoist A-frags; on-the-fly x~ -> -2*x~ (sign flip + exp+1, 0 <= x < 2)
    short8 Am[4], Ah[4];
#pragma unroll
    for (int ii = 0; ii < 4; ++ii) {
        const int ri = ((w << 2) + ii) * 16 + mrow;
        uint4 u = *(const uint4*)&xs[ri * XSTR + (quad << 3)];
        u.x = (u.x ^ 0x80008000u) + 0x00800080u;
        u.y = (u.y ^ 0x80008000u) + 0x00800080u;
        u.z = (u.z ^ 0x80008000u) + 0x00800080u;
        u.w = (u.w ^ 0x80008000u) + 0x00800080u;
        Am[ii] = *(const short8*)&u;
        Ah[ii] = (quad == 0) ? *(const short8*)&eA[ri << 3] : zfrag;
    }

    float acc[4] = {0.f, 0.f, 0.f, 0.f};
#pragma unroll 4
    for (int j = 0; j < 16; ++j) {
        const int cj = (j << 4) + mrow;
        short8 Bm = *(const short8*)&xs[cj * XSTR + (quad << 3)];
        short8 Bh = (quad == 0) ? *(const short8*)&eB[cj << 3] : zfrag;
        float4v g[4];
#pragma unroll
        for (int ii = 0; ii < 4; ++ii) {
            g[ii] = (float4v){0.f, 0.f, 0.f, 0.f};
            g[ii] = __builtin_amdgcn_mfma_f32_16x16x32_bf16(Ah[ii], Bh, g[ii], 0, 0, 0);
            g[ii] = __builtin_amdgcn_mfma_f32_16x16x32_bf16(Am[ii], Bm, g[ii], 0, 0, 0);
        }
#pragma unroll
        for (int ii = 0; ii < 4; ++ii) {
            acc[ii] += fabsf(g[ii][0]);
            acc[ii] += fabsf(g[ii][1]);
            acc[ii] += fabsf(g[ii][2]);
            acc[ii] += fabsf(g[ii][3]);
        }
    }
    float a = (acc[0] + acc[1]) + (acc[2] + acc[3]);

#pragma unroll
    for (int off = 32; off > 0; off >>= 1)
        a += __shfl_down(a, off, 64);
    if (lane == 0) red[w] = a;
    __syncthreads();
    if (t == 0)
        partial[b] = (red[0] + red[1]) + (red[2] + red[3]);
}

__global__ __launch_bounds__(256)
void reduce_kernel(const float* __restrict__ partial, float* __restrict__ out,
                   int n, float scale)
{
    __shared__ float red[4];
    float a = 0.f;
    for (int i = threadIdx.x; i < n; i += 256) a += partial[i];
#pragma unroll
    for (int off = 32; off > 0; off >>= 1)
        a += __shfl_down(a, off, 64);
    const int lane = threadIdx.x & 63, w = threadIdx.x >> 6;
    if (lane == 0) red[w] = a;
    __syncthreads();
    if (threadIdx.x == 0)
        out[0] = ((red[0] + red[1]) + (red[2] + red[3])) * scale;
}

extern "C" void kernel_launch(void* const* d_in, const int* in_sizes, int n_in,
                              void* d_out, int out_size, void* d_ws, size_t ws_size,
                              hipStream_t stream) {
    const float* msi   = (const float*)d_in[0];
    const float* he    = (const float*)d_in[1];
    const int*   i_idx = (const int*)d_in[2];
    const int*   j_idx = (const int*)d_in[3];
    const int    NB    = in_sizes[2];
    float*       out   = (float*)d_out;
    float*       part  = (float*)d_ws;        // NB floats of scratch

    const float scale = 1.0f / ((float)(PSZ * PSZ) * (float)(NB / 5));
    corr_loss_kernel<<<NB, 256, 0, stream>>>(msi, he, i_idx, j_idx, part);
    reduce_kernel<<<1, 256, 0, stream>>>(part, out, NB, scale);
}